// Round 2
// baseline (8415.372 us; speedup 1.0000x reference)
//
#include <hip/hip_runtime.h>
#include <cstdint>
#include <cstddef>

// Problem dims (from setup_inputs): B=4, H=192, W=640, C=64, sr=2
// Conv chans: 69 -> 128 -> 128 -> 96 -> 64 -> 32 -> 1, all 3x3 SAME, NHWC/HWIO.
//
// Round 1 change: round 0 used ~639 MB of d_ws without checking ws_size ->
// probable OOB write -> HSA memory-fault abort. Now the batch dim is processed
// in tiles of nb batches (nb chosen host-side from ws_size; 1 batch needs only
// 120 MiB: two ping-pong buffers of H*W*128 fp32). Costs(69ch) lives in buffer
// X, warped(64ch) in buffer Y; chain X/Y ping-pong ends in d_out.

#define LEAKY_SLOPE 0.2f

__device__ __forceinline__ float leaky(float v) { return v >= 0.f ? v : LEAKY_SLOPE * v; }

// ---------------------------------------------------------------------------
// Kernel 1: bilinear 2x upsample of prev_disp (half-pixel, clamped) + horizontal
// warp of `right` by disp. One thread per (b,h,w) within the batch tile.
// ---------------------------------------------------------------------------
__global__ __launch_bounds__(256) void warp_kernel(
    const float* __restrict__ right, const float* __restrict__ prev,
    float* __restrict__ warped, int H, int W, int C, int npx)
{
    int idx = blockIdx.x * 256 + threadIdx.x;
    if (idx >= npx) return;
    int w = idx % W;
    int t = idx / W;
    int h = t % H;
    int b = t / H;          // batch index local to this tile
    int H2 = H >> 1, W2 = W >> 1;

    // half-pixel bilinear: src = (dst+0.5)*0.5 - 0.5, edge-clamped indices
    float sy = 0.5f * (float)h - 0.25f;
    float sx = 0.5f * (float)w - 0.25f;
    float y0f = floorf(sy), x0f = floorf(sx);
    float fy = sy - y0f, fx = sx - x0f;
    int y0 = (int)y0f, x0 = (int)x0f;
    int y0c = min(max(y0, 0), H2 - 1), y1c = min(max(y0 + 1, 0), H2 - 1);
    int x0c = min(max(x0, 0), W2 - 1), x1c = min(max(x0 + 1, 0), W2 - 1);
    const float* pb = prev + (size_t)b * H2 * W2;
    float p00 = pb[y0c * W2 + x0c], p01 = pb[y0c * W2 + x1c];
    float p10 = pb[y1c * W2 + x0c], p11 = pb[y1c * W2 + x1c];
    float disp = (1.f - fy) * ((1.f - fx) * p00 + fx * p01)
               + fy * ((1.f - fx) * p10 + fx * p11);

    // warp: sample right at x = w + disp (reference _warp_right semantics)
    float cx = (float)w + disp;
    float xf0 = floorf(cx);
    float xf1 = xf0 + 1.f;
    float xmax = (float)(W - 1);
    float x0s = fminf(fmaxf(xf0, 0.f), xmax);
    float x1s = fminf(fmaxf(xf1, 0.f), xmax);
    float wt0 = (xf1 - cx) * (xf0 == x0s ? 1.f : 0.f);
    float wt1 = (cx - xf0) * (xf1 == x1s ? 1.f : 0.f);
    int i0 = (int)x0s, i1 = (int)x1s;

    const float* r0 = right + ((size_t)(b * H + h) * W + i0) * C;
    const float* r1 = right + ((size_t)(b * H + h) * W + i1) * C;
    float* o = warped + (size_t)idx * C;
    for (int c = 0; c < C; c += 4) {
        float4 v0 = *(const float4*)(r0 + c);
        float4 v1 = *(const float4*)(r1 + c);
        float4 vo;
        vo.x = wt0 * v0.x + wt1 * v1.x;
        vo.y = wt0 * v0.y + wt1 * v1.y;
        vo.z = wt0 * v0.z + wt1 * v1.z;
        vo.w = wt0 * v0.w + wt1 * v1.w;
        *(float4*)(o + c) = vo;
    }
}

// ---------------------------------------------------------------------------
// Kernel 2: cost volume + concat. costs[...,0:64]=left, [64:69]=mean_c(
// left * warped shifted by d-2), zero outside W. One thread per pixel.
// ---------------------------------------------------------------------------
__global__ __launch_bounds__(256) void costs_kernel(
    const float* __restrict__ left, const float* __restrict__ warped,
    float* __restrict__ costs, int W, int npx)
{
    int idx = blockIdx.x * 256 + threadIdx.x;
    if (idx >= npx) return;
    int w = idx % W;

    const float* L = left + (size_t)idx * 64;
    float* O = costs + (size_t)idx * 69;

    float dot[5] = {0.f, 0.f, 0.f, 0.f, 0.f};
    bool ok[5];
    const float* Wp[5];
#pragma unroll
    for (int d = 0; d < 5; ++d) {
        int x = w + d - 2;
        ok[d] = (x >= 0) && (x < W);
        Wp[d] = warped + ((size_t)idx + (d - 2)) * 64;
    }
    for (int c = 0; c < 64; c += 4) {
        float4 l4 = *(const float4*)(L + c);
        O[c + 0] = l4.x; O[c + 1] = l4.y; O[c + 2] = l4.z; O[c + 3] = l4.w;
#pragma unroll
        for (int d = 0; d < 5; ++d) {
            if (ok[d]) {
                float4 w4 = *(const float4*)(Wp[d] + c);
                dot[d] += l4.x * w4.x + l4.y * w4.y + l4.z * w4.z + l4.w * w4.w;
            }
        }
    }
#pragma unroll
    for (int d = 0; d < 5; ++d) O[64 + d] = dot[d] * (1.f / 64.f);
}

// ---------------------------------------------------------------------------
// Kernel 3 (template): 3x3 SAME conv, NHWC, HWIO weights, optional leaky-relu.
// Block: 256 threads = TX px-groups x TY co-groups; each thread 4 px x 4 co.
// Per-dy: stage (PX+2) x CIN input row into LDS (stride PX+4 keeps float4
// alignment and breaks pow2 bank strides), then accumulate over ci with
// 2x ds_read_b128 activations + float4 weight loads (L1-resident weights).
// blockIdx.y spans (tile batches)*H.
// ---------------------------------------------------------------------------
template <int CIN, int COUT, bool RELU>
__global__ __launch_bounds__(256) void conv3x3_kernel(
    const float* __restrict__ in, const float* __restrict__ wgt,
    const float* __restrict__ bias, float* __restrict__ out,
    int H, int W, int n_z)
{
    constexpr int TY = (COUT >= 64) ? 16 : (COUT / 4);  // co groups per block
    constexpr int TX = 256 / TY;                        // px groups per block
    constexpr int PX = TX * 4;                          // pixels per block
    constexpr int STRIDE = PX + 4;                      // LDS row stride (floats)
    __shared__ float lds[CIN * STRIDE];

    const int tid = threadIdx.x;
    const int tx = tid % TX;
    const int ty = tid / TX;
    const int pxt = blockIdx.x / n_z;
    const int zco = blockIdx.x % n_z;
    const int w0 = pxt * PX;
    const int hh = blockIdx.y % H;
    const int bb = blockIdx.y / H;   // batch local to tile
    const int co0 = zco * 64 + ty * 4;
    const int co0c = min(co0, COUT - 4);  // clamp for idle threads (COUT=96 tail)

    float acc[4][4];
#pragma unroll
    for (int p = 0; p < 4; ++p)
#pragma unroll
        for (int c = 0; c < 4; ++c) acc[p][c] = 0.f;

    for (int dy = -1; dy <= 1; ++dy) {
        int h = hh + dy;
        bool rowok = (h >= 0) && (h < H);
        __syncthreads();  // protect LDS from previous iteration's readers
        if (rowok) {
            const float* src = in + (size_t)(bb * H + h) * W * CIN;
            for (int i = tid; i < (PX + 2) * CIN; i += 256) {
                int p = i / CIN;
                int ci = i - p * CIN;
                int x = w0 - 1 + p;
                float v = (x >= 0 && x < W) ? src[(size_t)x * CIN + ci] : 0.f;
                lds[ci * STRIDE + p] = v;
            }
        }
        __syncthreads();
        if (!rowok) continue;  // uniform across block

        const float* wrow = wgt + (size_t)((dy + 1) * 3) * CIN * COUT;
        for (int ci = 0; ci < CIN; ++ci) {
            const float4 a0 = *(const float4*)(&lds[ci * STRIDE + tx * 4]);
            const float4 a1 = *(const float4*)(&lds[ci * STRIDE + tx * 4 + 4]);
            float av[8] = {a0.x, a0.y, a0.z, a0.w, a1.x, a1.y, a1.z, a1.w};
#pragma unroll
            for (int dx = 0; dx < 3; ++dx) {
                const float4 wv = *(const float4*)(wrow + ((size_t)dx * CIN + ci) * COUT + co0c);
#pragma unroll
                for (int p = 0; p < 4; ++p) {
                    float iv = av[p + dx];  // px_h = tx*4 + p + dx (halo base -1)
                    acc[p][0] += iv * wv.x;
                    acc[p][1] += iv * wv.y;
                    acc[p][2] += iv * wv.z;
                    acc[p][3] += iv * wv.w;
                }
            }
        }
    }

    if (co0 <= COUT - 4) {
        float4 bv = *(const float4*)(bias + co0);
        const size_t row_base = (size_t)(bb * H + hh) * W;
#pragma unroll
        for (int p = 0; p < 4; ++p) {
            int x = w0 + tx * 4 + p;  // W divisible by PX -> always in bounds
            float4 v;
            v.x = acc[p][0] + bv.x;
            v.y = acc[p][1] + bv.y;
            v.z = acc[p][2] + bv.z;
            v.w = acc[p][3] + bv.w;
            if (RELU) {
                v.x = leaky(v.x); v.y = leaky(v.y);
                v.z = leaky(v.z); v.w = leaky(v.w);
            }
            *(float4*)(out + (row_base + x) * COUT + co0) = v;
        }
    }
}

// ---------------------------------------------------------------------------
// Kernel 4: final conv, CIN=32 -> COUT=1, linear. One thread per pixel.
// ---------------------------------------------------------------------------
__global__ __launch_bounds__(256) void conv_last_kernel(
    const float* __restrict__ in, const float* __restrict__ wgt,
    const float* __restrict__ bias, float* __restrict__ out,
    int H, int W, int npx)
{
    int idx = blockIdx.x * 256 + threadIdx.x;
    if (idx >= npx) return;
    int w = idx % W;
    int t = idx / W;
    int h = t % H;
    int b = t / H;

    float acc = bias[0];
#pragma unroll
    for (int dy = 0; dy < 3; ++dy) {
        int hy = h + dy - 1;
        if (hy < 0 || hy >= H) continue;
#pragma unroll
        for (int dx = 0; dx < 3; ++dx) {
            int x = w + dx - 1;
            if (x < 0 || x >= W) continue;
            const float* p = in + ((size_t)(b * H + hy) * W + x) * 32;
            const float* wk = wgt + (dy * 3 + dx) * 32;
#pragma unroll
            for (int c = 0; c < 32; c += 4) {
                float4 v = *(const float4*)(p + c);
                float4 wv = *(const float4*)(wk + c);
                acc += v.x * wv.x + v.y * wv.y + v.z * wv.z + v.w * wv.w;
            }
        }
    }
    out[idx] = acc;
}

// ---------------------------------------------------------------------------
extern "C" void kernel_launch(void* const* d_in, const int* in_sizes, int n_in,
                              void* d_out, int out_size, void* d_ws, size_t ws_size,
                              hipStream_t stream)
{
    constexpr int B = 4, H = 192, W = 640, C = 64;
    constexpr int HW = H * W;  // 122880 px per batch

    const float* left  = (const float*)d_in[0];
    const float* right = (const float*)d_in[1];
    const float* prev  = (const float*)d_in[2];
    // d_in[3] = search_range (int scalar) == 2, baked into kernels
    const float* w1 = (const float*)d_in[4];
    const float* b1 = (const float*)d_in[5];
    const float* w2 = (const float*)d_in[6];
    const float* b2 = (const float*)d_in[7];
    const float* w3 = (const float*)d_in[8];
    const float* b3 = (const float*)d_in[9];
    const float* w4 = (const float*)d_in[10];
    const float* b4 = (const float*)d_in[11];
    const float* w5 = (const float*)d_in[12];
    const float* b5 = (const float*)d_in[13];
    const float* w6 = (const float*)d_in[14];
    const float* b6 = (const float*)d_in[15];
    float* out = (float*)d_out;

    // Batch-tile size from ws_size (host-constant -> graph-capture safe).
    // Per batch: two ping-pong buffers of HW*128 floats = 120 MiB total.
    const size_t per_batch_bytes = 2ull * HW * 128 * sizeof(float);
    int nb = 1;
    if (ws_size >= 4 * per_batch_bytes) nb = 4;
    else if (ws_size >= 2 * per_batch_bytes) nb = 2;

    const int H2 = H / 2, W2 = W / 2;
    dim3 blk(256);

    for (int b0 = 0; b0 < B; b0 += nb) {
        const int npx = nb * HW;
        const int pxblocks = (npx + 255) / 256;
        float* ws = (float*)d_ws;
        float* X = ws;                          // costs(69) / c2(128) / c4(64)
        float* Y = X + (size_t)nb * HW * 128;   // warped(64) / c1(128) / c3(96) / c5(32)

        const float* leftb  = left  + (size_t)b0 * HW * C;
        const float* rightb = right + (size_t)b0 * HW * C;
        const float* prevb  = prev  + (size_t)b0 * H2 * W2;
        float* outb = out + (size_t)b0 * HW;

        warp_kernel<<<pxblocks, blk, 0, stream>>>(rightb, prevb, Y, H, W, C, npx);
        costs_kernel<<<pxblocks, blk, 0, stream>>>(leftb, Y, X, W, npx);

        // conv1: 69 -> 128 (relu), X -> Y
        conv3x3_kernel<69, 128, true><<<dim3((W / 64) * 2, nb * H), blk, 0, stream>>>(
            X, w1, b1, Y, H, W, 2);
        // conv2: 128 -> 128 (relu), Y -> X
        conv3x3_kernel<128, 128, true><<<dim3((W / 64) * 2, nb * H), blk, 0, stream>>>(
            Y, w2, b2, X, H, W, 2);
        // conv3: 128 -> 96 (relu), X -> Y
        conv3x3_kernel<128, 96, true><<<dim3((W / 64) * 2, nb * H), blk, 0, stream>>>(
            X, w3, b3, Y, H, W, 2);
        // conv4: 96 -> 64 (relu), Y -> X
        conv3x3_kernel<96, 64, true><<<dim3((W / 64) * 1, nb * H), blk, 0, stream>>>(
            Y, w4, b4, X, H, W, 1);
        // conv5: 64 -> 32 (relu), X -> Y  (TY=8 -> 128 px per block)
        conv3x3_kernel<64, 32, true><<<dim3((W / 128) * 1, nb * H), blk, 0, stream>>>(
            X, w5, b5, Y, H, W, 1);
        // conv6: 32 -> 1 (linear), Y -> outb
        conv_last_kernel<<<pxblocks, blk, 0, stream>>>(Y, w6, b6, outb, H, W, npx);
    }
}

// Round 3
// 1280.062 us; speedup vs baseline: 6.5742x; 6.5742x over previous
//
#include <hip/hip_runtime.h>
#include <cstdint>
#include <cstddef>

// Problem dims: B=4, H=192, W=640, C=64, sr=2
// Conv chans: 69 -> 128 -> 128 -> 96 -> 64 -> 32 -> 1, 3x3 SAME, NHWC/HWIO.
//
// Round 2 -> 3: move conv1-5 to bf16 MFMA (32x32x16), activations bf16 in ws
// (channel-padded: costs 69->96 zeros), weights pre-packed per layer into
// B-fragment order. Warp+costs fused into one LDS-tiled kernel (round-2 profile
// showed costs_kernel at 9x HBM over-fetch from L1/L2 thrash).

#define LEAKY_SLOPE 0.2f

typedef float  f32x16 __attribute__((ext_vector_type(16)));
typedef short  s16x8  __attribute__((ext_vector_type(8)));
typedef short  s16x4  __attribute__((ext_vector_type(4)));

__device__ __forceinline__ unsigned short f2bf(float f) {
    unsigned u = __float_as_uint(f);
    u += 0x7FFFu + ((u >> 16) & 1u);          // round-to-nearest-even
    return (unsigned short)(u >> 16);
}
__device__ __forceinline__ float bf2f(unsigned short s) {
    return __uint_as_float(((unsigned)s) << 16);
}
__device__ __forceinline__ float leaky(float v){ return v >= 0.f ? v : LEAKY_SLOPE * v; }

// ---------------------------------------------------------------------------
// Pack HWIO fp32 weights into bf16 B-fragment order for mfma_32x32x16_bf16:
// flat = ((((dydx*KB + kb)*NT + nt)*64 + lane)*8 + j
// value = w[dydx][ci = kb*16 + (lane>>5)*8 + j][co = nt*32 + (lane&31)]
// (zero-padded for ci >= CIN; k-order matches the A-side fragment exactly).
// ---------------------------------------------------------------------------
__global__ __launch_bounds__(256) void pack_weights(
    const float* __restrict__ src, short* __restrict__ dst,
    int CIN, int COUT, int KB, int NT, int total)
{
    int i = blockIdx.x * 256 + threadIdx.x;
    if (i >= total) return;
    int j    = i & 7;
    int lane = (i >> 3) & 63;
    int r    = i >> 9;
    int nt = r % NT; r /= NT;
    int kb = r % KB;
    int dydx = r / KB;
    int ci = kb * 16 + ((lane >> 5) << 3) + j;
    int co = nt * 32 + (lane & 31);
    float v = (ci < CIN) ? src[((size_t)dydx * CIN + ci) * COUT + co] : 0.f;
    dst[i] = (short)f2bf(v);
}

// ---------------------------------------------------------------------------
// Fused upsample + warp + cost-volume. Block = 64 px of one row.
// Output: bf16 [px][96]: ch0..63 = left, 64..68 = cost dots, 69..95 = 0.
// All left/right data staged through LDS once, coalesced.
// ---------------------------------------------------------------------------
__global__ __launch_bounds__(256) void warp_costs_kernel(
    const float* __restrict__ left, const float* __restrict__ right,
    const float* __restrict__ prev, short* __restrict__ out,
    int H, int W)
{
    __shared__ float wt0s[68], wt1s[68];
    __shared__ int   i0s[68],  i1s[68];
    __shared__ __align__(16) short warp_s[68 * 68];  // [px -2..65][64ch], stride 68
    __shared__ __align__(16) short left_s[64 * 68];

    const int tid = threadIdx.x;
    const int w0 = blockIdx.x * 64;
    const int hh = blockIdx.y % H;
    const int bb = blockIdx.y / H;
    const int H2 = H >> 1, W2 = W >> 1;

    if (tid < 68) {
        int w = w0 - 2 + tid;
        // half-pixel bilinear upsample of prev_disp
        float sy = 0.5f * (float)hh - 0.25f;
        float sx = 0.5f * (float)w  - 0.25f;
        float y0f = floorf(sy), x0f = floorf(sx);
        float fy = sy - y0f, fx = sx - x0f;
        int y0 = (int)y0f, x0 = (int)x0f;
        int y0c = min(max(y0, 0), H2 - 1), y1c = min(max(y0 + 1, 0), H2 - 1);
        int x0c = min(max(x0, 0), W2 - 1), x1c = min(max(x0 + 1, 0), W2 - 1);
        const float* pb = prev + (size_t)bb * H2 * W2;
        float p00 = pb[y0c * W2 + x0c], p01 = pb[y0c * W2 + x1c];
        float p10 = pb[y1c * W2 + x0c], p11 = pb[y1c * W2 + x1c];
        float disp = (1.f - fy) * ((1.f - fx) * p00 + fx * p01)
                   + fy * ((1.f - fx) * p10 + fx * p11);
        // horizontal warp weights
        float cx = (float)w + disp;
        float xf0 = floorf(cx), xf1 = xf0 + 1.f;
        float xmax = (float)(W - 1);
        float x0s = fminf(fmaxf(xf0, 0.f), xmax);
        float x1s = fminf(fmaxf(xf1, 0.f), xmax);
        wt0s[tid] = (xf1 - cx) * (xf0 == x0s ? 1.f : 0.f);
        wt1s[tid] = (cx - xf0) * (xf1 == x1s ? 1.f : 0.f);
        i0s[tid] = (int)x0s;
        i1s[tid] = (int)x1s;
    }
    __syncthreads();

    const float* rrow = right + (size_t)(bb * H + hh) * W * 64;
    const float* lrow = left  + (size_t)(bb * H + hh) * W * 64;
    const size_t obase = ((size_t)(bb * H + hh) * W + w0) * 96;

    // warped tile (68 px x 64 ch) -> LDS bf16
    for (int u = tid; u < 68 * 16; u += 256) {
        int px = u >> 4, c4 = (u & 15) * 4;
        float a = wt0s[px], b = wt1s[px];
        const float4 r0 = *(const float4*)(rrow + (size_t)i0s[px] * 64 + c4);
        const float4 r1 = *(const float4*)(rrow + (size_t)i1s[px] * 64 + c4);
        s16x4 o;
        o[0] = (short)f2bf(a * r0.x + b * r1.x);
        o[1] = (short)f2bf(a * r0.y + b * r1.y);
        o[2] = (short)f2bf(a * r0.z + b * r1.z);
        o[3] = (short)f2bf(a * r0.w + b * r1.w);
        *(s16x4*)(warp_s + px * 68 + c4) = o;
    }
    // left tile -> LDS bf16 + out ch0..63
    for (int u = tid; u < 64 * 16; u += 256) {
        int px = u >> 4, c4 = (u & 15) * 4;
        const float4 l = *(const float4*)(lrow + ((size_t)(w0 + px)) * 64 + c4);
        s16x4 o;
        o[0] = (short)f2bf(l.x);
        o[1] = (short)f2bf(l.y);
        o[2] = (short)f2bf(l.z);
        o[3] = (short)f2bf(l.w);
        *(s16x4*)(left_s + px * 68 + c4) = o;
        *(s16x4*)(out + obase + (size_t)px * 96 + c4) = o;
    }
    // zero pad ch 72..95 (3 x 8ch vectors) and 69..71
    for (int u = tid; u < 64 * 3; u += 256) {
        int px = u / 3, c = 72 + (u % 3) * 8;
        s16x8 z = {0,0,0,0,0,0,0,0};
        *(s16x8*)(out + obase + (size_t)px * 96 + c) = z;
    }
    if (tid < 64) {
        out[obase + (size_t)tid * 96 + 69] = 0;
        out[obase + (size_t)tid * 96 + 70] = 0;
        out[obase + (size_t)tid * 96 + 71] = 0;
    }
    __syncthreads();

    // cost dots: wave d = tid>>6 handles shift d (0..3), then wave 0 does d=4.
    {
        int px = tid & 63;
        int d = tid >> 6;
        for (int pass = 0; pass < 2; ++pass) {
            if (pass == 1) { if (tid >= 64) break; d = 4; }
            int x = w0 + px + d - 2;
            float s = 0.f;
            if (x >= 0 && x < W) {
                const short* lp = left_s + px * 68;
                const short* wp = warp_s + (px + d) * 68;
                for (int c = 0; c < 64; ++c)
                    s += bf2f((unsigned short)lp[c]) * bf2f((unsigned short)wp[c]);
            }
            out[obase + (size_t)px * 96 + 64 + d] = (short)f2bf(s * (1.f / 64.f));
        }
    }
}

// ---------------------------------------------------------------------------
// bf16 MFMA 3x3 conv (implicit GEMM, mfma_f32_32x32x16_bf16).
// Block = 256 thr (4 waves), 128 px of one row, all COUT.
// COUT>=96: waves 2x2 (m-half 64px x n-half); COUT<96: 4-way m-split (32px ea).
// A staged per-dy in LDS, bf16, XOR-swizzled at 8-ch granularity (bank-even).
// B read from pre-packed global (L1/L2-resident).
// ---------------------------------------------------------------------------
template <int CINP, int COUT, bool RELU>
__global__ __launch_bounds__(256) void conv_mfma(
    const short* __restrict__ in, const short* __restrict__ wp,
    const float* __restrict__ bias, short* __restrict__ out,
    int H, int W)
{
    constexpr int KB  = CINP / 16;                 // K-steps per (dy,dx)
    constexpr int NT  = COUT / 32;                 // n-tiles total
    constexpr int SL8 = (CINP == 96) ? 16 : CINP / 8;  // LDS ch8-slots/px (pow2)
    constexpr bool BIGN = (COUT >= 96);
    constexpr int MT  = BIGN ? 2 : 1;              // m-tiles per wave
    constexpr int NTW = BIGN ? 2 : NT;             // n-tiles per wave
    __shared__ __align__(16) short lds[132 * SL8 * 8];

    const int tid  = threadIdx.x;
    const int lane = tid & 63;
    const int wave = tid >> 6;
    const int w0 = blockIdx.x * 128;
    const int hh = blockIdx.y % H;
    const int bb = blockIdx.y / H;

    const int wm = BIGN ? (wave >> 1) : wave;
    const int wn = BIGN ? (wave & 1) : 0;
    const int mbase = wm * (BIGN ? 64 : 32);
    const int l31 = lane & 31;
    const int lhi = lane >> 5;

    f32x16 acc[MT][NTW];
#pragma unroll
    for (int mt = 0; mt < MT; ++mt)
#pragma unroll
        for (int nt = 0; nt < NTW; ++nt)
#pragma unroll
            for (int r = 0; r < 16; ++r) acc[mt][nt][r] = 0.f;

    for (int dy = 0; dy < 3; ++dy) {
        __syncthreads();
        const int h = hh + dy - 1;
        const bool rowok = (h >= 0) && (h < H);
        const short* src = in + (size_t)(bb * H + h) * W * CINP;
        for (int u = tid; u < 130 * (CINP / 8); u += 256) {
            int px = u / (CINP / 8);
            int c8 = u - px * (CINP / 8);
            int x = w0 - 1 + px;
            s16x8 v = {0,0,0,0,0,0,0,0};
            if (rowok && x >= 0 && x < W)
                v = *(const s16x8*)(src + (size_t)x * CINP + c8 * 8);
            *(s16x8*)(&lds[(px * SL8 + (c8 ^ (px & 7))) * 8]) = v;
        }
        __syncthreads();

        for (int dx = 0; dx < 3; ++dx) {
            const short* wdx = wp + (size_t)(dy * 3 + dx) * KB * NT * 512;
            for (int kb = 0; kb < KB; ++kb) {
                const int c8r = kb * 2 + lhi;       // 8-ch block this half-wave reads
                s16x8 a[MT];
#pragma unroll
                for (int mt = 0; mt < MT; ++mt) {
                    int px = mbase + mt * 32 + l31 + dx;
                    a[mt] = *(const s16x8*)(&lds[(px * SL8 + (c8r ^ (px & 7))) * 8]);
                }
                const short* wkb = wdx + (size_t)kb * NT * 512;
#pragma unroll
                for (int nt = 0; nt < NTW; ++nt) {
                    const int tile = BIGN ? (wn * 2 + nt) : nt;
                    if (BIGN && tile >= NT) continue;   // COUT=96, wn=1: only tile 2
                    s16x8 b = *(const s16x8*)(wkb + ((size_t)tile * 64 + lane) * 8);
#pragma unroll
                    for (int mt = 0; mt < MT; ++mt)
                        acc[mt][nt] = __builtin_amdgcn_mfma_f32_32x32x16_bf16(
                            a[mt], b, acc[mt][nt], 0, 0, 0);
                }
            }
        }
    }

    // epilogue: C/D layout col(co)=lane&31, row(px)=(r&3)+8*(r>>2)+4*(lane>>5)
    const size_t rowbase = (size_t)(bb * H + hh) * W + w0;
#pragma unroll
    for (int nt = 0; nt < NTW; ++nt) {
        const int tile = BIGN ? (wn * 2 + nt) : nt;
        if (BIGN && tile >= NT) continue;
        const int co = tile * 32 + l31;
        const float bv = bias[co];
#pragma unroll
        for (int mt = 0; mt < MT; ++mt) {
            const int pxb = mbase + mt * 32 + 4 * lhi;
#pragma unroll
            for (int r = 0; r < 16; ++r) {
                int px = pxb + (r & 3) + 8 * (r >> 2);
                float v = acc[mt][nt][r] + bv;
                if (RELU) v = leaky(v);
                out[(rowbase + px) * COUT + co] = (short)f2bf(v);
            }
        }
    }
}

// ---------------------------------------------------------------------------
// Final conv 32 -> 1, linear, bf16 in / fp32 out. One thread per pixel.
// ---------------------------------------------------------------------------
__global__ __launch_bounds__(256) void conv_last_kernel(
    const short* __restrict__ in, const float* __restrict__ wgt,
    const float* __restrict__ bias, float* __restrict__ out,
    int H, int W, int npx)
{
    int idx = blockIdx.x * 256 + threadIdx.x;
    if (idx >= npx) return;
    int w = idx % W;
    int t = idx / W;
    int h = t % H;
    int b = t / H;

    float acc = bias[0];
#pragma unroll
    for (int dy = 0; dy < 3; ++dy) {
        int hy = h + dy - 1;
        if (hy < 0 || hy >= H) continue;
#pragma unroll
        for (int dx = 0; dx < 3; ++dx) {
            int x = w + dx - 1;
            if (x < 0 || x >= W) continue;
            const short* p = in + ((size_t)(b * H + hy) * W + x) * 32;
            const float* wk = wgt + (dy * 3 + dx) * 32;
#pragma unroll
            for (int c8 = 0; c8 < 4; ++c8) {
                s16x8 v = *(const s16x8*)(p + c8 * 8);
#pragma unroll
                for (int k = 0; k < 8; ++k)
                    acc += bf2f((unsigned short)v[k]) * wk[c8 * 8 + k];
            }
        }
    }
    out[idx] = acc;
}

// ---------------------------------------------------------------------------
extern "C" void kernel_launch(void* const* d_in, const int* in_sizes, int n_in,
                              void* d_out, int out_size, void* d_ws, size_t ws_size,
                              hipStream_t stream)
{
    constexpr int B = 4, H = 192, W = 640;
    constexpr int HW = H * W;          // 122880

    const float* left  = (const float*)d_in[0];
    const float* right = (const float*)d_in[1];
    const float* prev  = (const float*)d_in[2];
    const float* w1 = (const float*)d_in[4];
    const float* b1 = (const float*)d_in[5];
    const float* w2 = (const float*)d_in[6];
    const float* b2 = (const float*)d_in[7];
    const float* w3 = (const float*)d_in[8];
    const float* b3 = (const float*)d_in[9];
    const float* w4 = (const float*)d_in[10];
    const float* b4 = (const float*)d_in[11];
    const float* w5 = (const float*)d_in[12];
    const float* b5 = (const float*)d_in[13];
    const float* w6 = (const float*)d_in[14];
    const float* b6 = (const float*)d_in[15];
    float* out = (float*)d_out;

    // Packed-weight region (shorts), then bf16 activation ping-pong X/Y.
    constexpr int S1 = 9 * 6 * 4 * 512;   // conv1: CINP 96,  COUT 128
    constexpr int S2 = 9 * 8 * 4 * 512;   // conv2: 128 -> 128
    constexpr int S3 = 9 * 8 * 3 * 512;   // conv3: 128 -> 96
    constexpr int S4 = 9 * 6 * 2 * 512;   // conv4: 96  -> 64
    constexpr int S5 = 9 * 4 * 1 * 512;   // conv5: 64  -> 32
    constexpr int P1 = 0, P2 = P1 + S1, P3 = P2 + S2, P4 = P3 + S3, P5 = P4 + S4;
    constexpr size_t WPAD = 524288;       // 1 MiB reserved (in shorts)

    short* wsS = (short*)d_ws;
    pack_weights<<<(S1 + 255) / 256, 256, 0, stream>>>(w1, wsS + P1,  69, 128, 6, 4, S1);
    pack_weights<<<(S2 + 255) / 256, 256, 0, stream>>>(w2, wsS + P2, 128, 128, 8, 4, S2);
    pack_weights<<<(S3 + 255) / 256, 256, 0, stream>>>(w3, wsS + P3, 128,  96, 8, 3, S3);
    pack_weights<<<(S4 + 255) / 256, 256, 0, stream>>>(w4, wsS + P4,  96,  64, 6, 2, S4);
    pack_weights<<<(S5 + 255) / 256, 256, 0, stream>>>(w5, wsS + P5,  64,  32, 4, 1, S5);

    // batch tiling from ws_size (deterministic -> graph-capture safe)
    auto need = [&](int nb) -> size_t {
        return (WPAD + 2ull * nb * HW * 128) * sizeof(short);
    };
    int nb = 1;
    if (ws_size >= need(4)) nb = 4;
    else if (ws_size >= need(2)) nb = 2;

    const int H2 = H / 2, W2 = W / 2;

    for (int b0 = 0; b0 < B; b0 += nb) {
        const int npx = nb * HW;
        short* X = wsS + WPAD;
        short* Y = X + (size_t)nb * HW * 128;

        const float* leftb  = left  + (size_t)b0 * HW * 64;
        const float* rightb = right + (size_t)b0 * HW * 64;
        const float* prevb  = prev  + (size_t)b0 * H2 * W2;
        float* outb = out + (size_t)b0 * HW;

        warp_costs_kernel<<<dim3(W / 64, nb * H), 256, 0, stream>>>(
            leftb, rightb, prevb, X, H, W);

        conv_mfma< 96, 128, true><<<dim3(W / 128, nb * H), 256, 0, stream>>>(
            X, wsS + P1, b1, Y, H, W);
        conv_mfma<128, 128, true><<<dim3(W / 128, nb * H), 256, 0, stream>>>(
            Y, wsS + P2, b2, X, H, W);
        conv_mfma<128,  96, true><<<dim3(W / 128, nb * H), 256, 0, stream>>>(
            X, wsS + P3, b3, Y, H, W);
        conv_mfma< 96,  64, true><<<dim3(W / 128, nb * H), 256, 0, stream>>>(
            Y, wsS + P4, b4, X, H, W);
        conv_mfma< 64,  32, true><<<dim3(W / 128, nb * H), 256, 0, stream>>>(
            X, wsS + P5, b5, Y, H, W);

        conv_last_kernel<<<(npx + 255) / 256, 256, 0, stream>>>(
            Y, w6, b6, outb, H, W, npx);
    }
}

// Round 4
// 1092.577 us; speedup vs baseline: 7.7023x; 1.1716x over previous
//
#include <hip/hip_runtime.h>
#include <cstdint>
#include <cstddef>

// Problem dims: B=4, H=192, W=640, C=64, sr=2
// Conv chans: 69 -> 128 -> 128 -> 96 -> 64 -> 32 -> 1, 3x3 SAME, NHWC/HWIO.
//
// Round 3 -> 4: round-3 profile showed conv_mfma latency/LDS-bound (MfmaUtil
// 11%, VALUBusy 8.7%, occupancy 21%): each A ds_read_b128 fed only 2 MFMAs ->
// LDS BW 2x oversubscribed. Now wave = 32-px m-slice and NTW = NT (one A-read
// feeds ALL n-tiles: 256 B LDS per MFMA = at the 128 B/cyc LDS roofline), all
// waves share B addresses (L1 broadcast), launch_bounds(256,3) for occupancy.

#define LEAKY_SLOPE 0.2f

typedef float  f32x16 __attribute__((ext_vector_type(16)));
typedef short  s16x8  __attribute__((ext_vector_type(8)));
typedef short  s16x4  __attribute__((ext_vector_type(4)));

__device__ __forceinline__ unsigned short f2bf(float f) {
    unsigned u = __float_as_uint(f);
    u += 0x7FFFu + ((u >> 16) & 1u);          // round-to-nearest-even
    return (unsigned short)(u >> 16);
}
__device__ __forceinline__ float bf2f(unsigned short s) {
    return __uint_as_float(((unsigned)s) << 16);
}
__device__ __forceinline__ float leaky(float v){ return v >= 0.f ? v : LEAKY_SLOPE * v; }

// ---------------------------------------------------------------------------
// Pack HWIO fp32 weights into bf16 B-fragment order for mfma_32x32x16_bf16:
// flat = (((dydx*KB + kb)*NT + nt)*64 + lane)*8 + j
// value = w[dydx][ci = kb*16 + (lane>>5)*8 + j][co = nt*32 + (lane&31)]
// ---------------------------------------------------------------------------
__global__ __launch_bounds__(256) void pack_weights(
    const float* __restrict__ src, short* __restrict__ dst,
    int CIN, int COUT, int KB, int NT, int total)
{
    int i = blockIdx.x * 256 + threadIdx.x;
    if (i >= total) return;
    int j    = i & 7;
    int lane = (i >> 3) & 63;
    int r    = i >> 9;
    int nt = r % NT; r /= NT;
    int kb = r % KB;
    int dydx = r / KB;
    int ci = kb * 16 + ((lane >> 5) << 3) + j;
    int co = nt * 32 + (lane & 31);
    float v = (ci < CIN) ? src[((size_t)dydx * CIN + ci) * COUT + co] : 0.f;
    dst[i] = (short)f2bf(v);
}

// ---------------------------------------------------------------------------
// Fused upsample + warp + cost-volume. Block = 64 px of one row.
// Output: bf16 [px][96]: ch0..63 = left, 64..68 = cost dots, 69..95 = 0.
// LDS strides are 72 shorts (144 B) for 16-B-aligned s16x8 access.
// ---------------------------------------------------------------------------
__global__ __launch_bounds__(256) void warp_costs_kernel(
    const float* __restrict__ left, const float* __restrict__ right,
    const float* __restrict__ prev, short* __restrict__ out,
    int H, int W)
{
    __shared__ float wt0s[68], wt1s[68];
    __shared__ int   i0s[68],  i1s[68];
    __shared__ __align__(16) short warp_s[68 * 72];  // [px -2..65][64ch]
    __shared__ __align__(16) short left_s[64 * 72];

    const int tid = threadIdx.x;
    const int w0 = blockIdx.x * 64;
    const int hh = blockIdx.y % H;
    const int bb = blockIdx.y / H;
    const int H2 = H >> 1, W2 = W >> 1;

    if (tid < 68) {
        int w = w0 - 2 + tid;
        float sy = 0.5f * (float)hh - 0.25f;
        float sx = 0.5f * (float)w  - 0.25f;
        float y0f = floorf(sy), x0f = floorf(sx);
        float fy = sy - y0f, fx = sx - x0f;
        int y0 = (int)y0f, x0 = (int)x0f;
        int y0c = min(max(y0, 0), H2 - 1), y1c = min(max(y0 + 1, 0), H2 - 1);
        int x0c = min(max(x0, 0), W2 - 1), x1c = min(max(x0 + 1, 0), W2 - 1);
        const float* pb = prev + (size_t)bb * H2 * W2;
        float p00 = pb[y0c * W2 + x0c], p01 = pb[y0c * W2 + x1c];
        float p10 = pb[y1c * W2 + x0c], p11 = pb[y1c * W2 + x1c];
        float disp = (1.f - fy) * ((1.f - fx) * p00 + fx * p01)
                   + fy * ((1.f - fx) * p10 + fx * p11);
        float cx = (float)w + disp;
        float xf0 = floorf(cx), xf1 = xf0 + 1.f;
        float xmax = (float)(W - 1);
        float x0s = fminf(fmaxf(xf0, 0.f), xmax);
        float x1s = fminf(fmaxf(xf1, 0.f), xmax);
        wt0s[tid] = (xf1 - cx) * (xf0 == x0s ? 1.f : 0.f);
        wt1s[tid] = (cx - xf0) * (xf1 == x1s ? 1.f : 0.f);
        i0s[tid] = (int)x0s;
        i1s[tid] = (int)x1s;
    }
    __syncthreads();

    const float* rrow = right + (size_t)(bb * H + hh) * W * 64;
    const float* lrow = left  + (size_t)(bb * H + hh) * W * 64;
    const size_t obase = ((size_t)(bb * H + hh) * W + w0) * 96;

    for (int u = tid; u < 68 * 16; u += 256) {
        int px = u >> 4, c4 = (u & 15) * 4;
        float a = wt0s[px], b = wt1s[px];
        const float4 r0 = *(const float4*)(rrow + (size_t)i0s[px] * 64 + c4);
        const float4 r1 = *(const float4*)(rrow + (size_t)i1s[px] * 64 + c4);
        s16x4 o;
        o[0] = (short)f2bf(a * r0.x + b * r1.x);
        o[1] = (short)f2bf(a * r0.y + b * r1.y);
        o[2] = (short)f2bf(a * r0.z + b * r1.z);
        o[3] = (short)f2bf(a * r0.w + b * r1.w);
        *(s16x4*)(warp_s + px * 72 + c4) = o;
    }
    for (int u = tid; u < 64 * 16; u += 256) {
        int px = u >> 4, c4 = (u & 15) * 4;
        const float4 l = *(const float4*)(lrow + ((size_t)(w0 + px)) * 64 + c4);
        s16x4 o;
        o[0] = (short)f2bf(l.x);
        o[1] = (short)f2bf(l.y);
        o[2] = (short)f2bf(l.z);
        o[3] = (short)f2bf(l.w);
        *(s16x4*)(left_s + px * 72 + c4) = o;
        *(s16x4*)(out + obase + (size_t)px * 96 + c4) = o;
    }
    // zero pad ch 69..95
    for (int u = tid; u < 64 * 3; u += 256) {
        int px = u / 3, c = 72 + (u % 3) * 8;
        s16x8 z = {0,0,0,0,0,0,0,0};
        *(s16x8*)(out + obase + (size_t)px * 96 + c) = z;
    }
    if (tid < 64) {
        out[obase + (size_t)tid * 96 + 69] = 0;
        out[obase + (size_t)tid * 96 + 70] = 0;
        out[obase + (size_t)tid * 96 + 71] = 0;
    }
    __syncthreads();

    // cost dots: 320 (px,d) tasks, vectorized s16x8 inner loop
    for (int u = tid; u < 64 * 5; u += 256) {
        int px = u / 5, d = u - px * 5;
        int x = w0 + px + d - 2;
        float s = 0.f;
        if (x >= 0 && x < W) {
            const short* lp = left_s + px * 72;
            const short* wq = warp_s + (px + d) * 72;
#pragma unroll
            for (int c8 = 0; c8 < 8; ++c8) {
                s16x8 l8 = *(const s16x8*)(lp + c8 * 8);
                s16x8 w8 = *(const s16x8*)(wq + c8 * 8);
#pragma unroll
                for (int k = 0; k < 8; ++k)
                    s += bf2f((unsigned short)l8[k]) * bf2f((unsigned short)w8[k]);
            }
        }
        out[obase + (size_t)px * 96 + 64 + d] = (short)f2bf(s * (1.f / 64.f));
    }
}

// ---------------------------------------------------------------------------
// bf16 MFMA 3x3 conv (implicit GEMM, mfma_f32_32x32x16_bf16).
// Block = 256 thr (4 waves) = 128 px of one row x all COUT.
// Wave w owns px [w*32, w*32+32); NTW = NT = COUT/32 (one A-read per kb feeds
// NT MFMAs -> 256 B LDS per MFMA for NT=4 = LDS BW roofline).
// A staged per-dy in LDS, XOR-swizzled at 8-ch granularity.
// B pre-packed; all 4 waves read identical B addresses (L1 broadcast).
// ---------------------------------------------------------------------------
template <int CINP, int COUT, bool RELU>
__global__ __launch_bounds__(256, 3) void conv_mfma(
    const short* __restrict__ in, const short* __restrict__ wp,
    const float* __restrict__ bias, short* __restrict__ out,
    int H, int W)
{
    constexpr int KB   = CINP / 16;                  // K-steps per (dy,dx)
    constexpr int NT   = COUT / 32;                  // n-tiles (all per wave)
    constexpr int CIN8 = CINP / 8;
    constexpr int SL8  = (CINP == 96) ? 16 : CIN8;   // LDS ch8-slots/px (pow2)
    __shared__ __align__(16) short lds[132 * SL8 * 8];

    const int tid  = threadIdx.x;
    const int lane = tid & 63;
    const int wave = tid >> 6;
    const int l31  = lane & 31;
    const int lhi  = lane >> 5;
    const int w0 = blockIdx.x * 128;
    const int hh = blockIdx.y % H;
    const int bb = blockIdx.y / H;

    f32x16 acc[NT];
#pragma unroll
    for (int nt = 0; nt < NT; ++nt)
#pragma unroll
        for (int r = 0; r < 16; ++r) acc[nt][r] = 0.f;

    for (int dy = 0; dy < 3; ++dy) {
        __syncthreads();
        const int h = hh + dy - 1;
        const bool rowok = (h >= 0) && (h < H);
        const short* src = in + (size_t)(bb * H + h) * W * CINP;
        for (int u = tid; u < 130 * CIN8; u += 256) {
            int px = u / CIN8;
            int c8 = u - px * CIN8;
            int x = w0 - 1 + px;
            s16x8 v = {0,0,0,0,0,0,0,0};
            if (rowok && x >= 0 && x < W)
                v = *(const s16x8*)(src + (size_t)x * CINP + c8 * 8);
            *(s16x8*)(&lds[(px * SL8 + (c8 ^ (px & 7))) * 8]) = v;
        }
        __syncthreads();

#pragma unroll
        for (int dx = 0; dx < 3; ++dx) {
            const short* wdx = wp + (size_t)((dy * 3 + dx) * KB) * NT * 512;
            const int px = wave * 32 + l31 + dx;
            const int pxs = px * SL8;
            const int pxx = px & 7;
#pragma unroll 2
            for (int kb = 0; kb < KB; ++kb) {
                const int c8r = kb * 2 + lhi;
                s16x8 a = *(const s16x8*)(&lds[(pxs + (c8r ^ pxx)) * 8]);
                s16x8 b[NT];
#pragma unroll
                for (int nt = 0; nt < NT; ++nt)
                    b[nt] = *(const s16x8*)(wdx + ((size_t)(kb * NT + nt) * 64 + lane) * 8);
#pragma unroll
                for (int nt = 0; nt < NT; ++nt)
                    acc[nt] = __builtin_amdgcn_mfma_f32_32x32x16_bf16(
                        a, b[nt], acc[nt], 0, 0, 0);
            }
        }
    }

    // epilogue: C/D layout col(co)=lane&31, row(px)=(r&3)+8*(r>>2)+4*(lane>>5)
    const size_t rowbase = (size_t)(bb * H + hh) * W + w0;
    const int pxb = wave * 32 + 4 * lhi;
#pragma unroll
    for (int nt = 0; nt < NT; ++nt) {
        const int co = nt * 32 + l31;
        const float bv = bias[co];
#pragma unroll
        for (int r = 0; r < 16; ++r) {
            int px = pxb + (r & 3) + 8 * (r >> 2);
            float v = acc[nt][r] + bv;
            if (RELU) v = leaky(v);
            out[(rowbase + px) * COUT + co] = (short)f2bf(v);
        }
    }
}

// ---------------------------------------------------------------------------
// Final conv 32 -> 1, linear, bf16 in / fp32 out. One thread per pixel.
// ---------------------------------------------------------------------------
__global__ __launch_bounds__(256) void conv_last_kernel(
    const short* __restrict__ in, const float* __restrict__ wgt,
    const float* __restrict__ bias, float* __restrict__ out,
    int H, int W, int npx)
{
    int idx = blockIdx.x * 256 + threadIdx.x;
    if (idx >= npx) return;
    int w = idx % W;
    int t = idx / W;
    int h = t % H;
    int b = t / H;

    float acc = bias[0];
#pragma unroll
    for (int dy = 0; dy < 3; ++dy) {
        int hy = h + dy - 1;
        if (hy < 0 || hy >= H) continue;
#pragma unroll
        for (int dx = 0; dx < 3; ++dx) {
            int x = w + dx - 1;
            if (x < 0 || x >= W) continue;
            const short* p = in + ((size_t)(b * H + hy) * W + x) * 32;
            const float* wk = wgt + (dy * 3 + dx) * 32;
#pragma unroll
            for (int c8 = 0; c8 < 4; ++c8) {
                s16x8 v = *(const s16x8*)(p + c8 * 8);
#pragma unroll
                for (int k = 0; k < 8; ++k)
                    acc += bf2f((unsigned short)v[k]) * wk[c8 * 8 + k];
            }
        }
    }
    out[idx] = acc;
}

// ---------------------------------------------------------------------------
extern "C" void kernel_launch(void* const* d_in, const int* in_sizes, int n_in,
                              void* d_out, int out_size, void* d_ws, size_t ws_size,
                              hipStream_t stream)
{
    constexpr int B = 4, H = 192, W = 640;
    constexpr int HW = H * W;          // 122880

    const float* left  = (const float*)d_in[0];
    const float* right = (const float*)d_in[1];
    const float* prev  = (const float*)d_in[2];
    const float* w1 = (const float*)d_in[4];
    const float* b1 = (const float*)d_in[5];
    const float* w2 = (const float*)d_in[6];
    const float* b2 = (const float*)d_in[7];
    const float* w3 = (const float*)d_in[8];
    const float* b3 = (const float*)d_in[9];
    const float* w4 = (const float*)d_in[10];
    const float* b4 = (const float*)d_in[11];
    const float* w5 = (const float*)d_in[12];
    const float* b5 = (const float*)d_in[13];
    const float* w6 = (const float*)d_in[14];
    const float* b6 = (const float*)d_in[15];
    float* out = (float*)d_out;

    // Packed-weight region (shorts), then bf16 activation ping-pong X/Y.
    constexpr int S1 = 9 * 6 * 4 * 512;   // conv1: CINP 96,  COUT 128
    constexpr int S2 = 9 * 8 * 4 * 512;   // conv2: 128 -> 128
    constexpr int S3 = 9 * 8 * 3 * 512;   // conv3: 128 -> 96
    constexpr int S4 = 9 * 6 * 2 * 512;   // conv4: 96  -> 64
    constexpr int S5 = 9 * 4 * 1 * 512;   // conv5: 64  -> 32
    constexpr int P1 = 0, P2 = P1 + S1, P3 = P2 + S2, P4 = P3 + S3, P5 = P4 + S4;
    constexpr size_t WPAD = 524288;       // 1 MiB reserved (in shorts)

    short* wsS = (short*)d_ws;
    pack_weights<<<(S1 + 255) / 256, 256, 0, stream>>>(w1, wsS + P1,  69, 128, 6, 4, S1);
    pack_weights<<<(S2 + 255) / 256, 256, 0, stream>>>(w2, wsS + P2, 128, 128, 8, 4, S2);
    pack_weights<<<(S3 + 255) / 256, 256, 0, stream>>>(w3, wsS + P3, 128,  96, 8, 3, S3);
    pack_weights<<<(S4 + 255) / 256, 256, 0, stream>>>(w4, wsS + P4,  96,  64, 6, 2, S4);
    pack_weights<<<(S5 + 255) / 256, 256, 0, stream>>>(w5, wsS + P5,  64,  32, 4, 1, S5);

    // batch tiling from ws_size (deterministic -> graph-capture safe)
    auto need = [&](int nb) -> size_t {
        return (WPAD + 2ull * nb * HW * 128) * sizeof(short);
    };
    int nb = 1;
    if (ws_size >= need(4)) nb = 4;
    else if (ws_size >= need(2)) nb = 2;

    const int H2 = H / 2, W2 = W / 2;

    for (int b0 = 0; b0 < B; b0 += nb) {
        const int npx = nb * HW;
        short* X = wsS + WPAD;
        short* Y = X + (size_t)nb * HW * 128;

        const float* leftb  = left  + (size_t)b0 * HW * 64;
        const float* rightb = right + (size_t)b0 * HW * 64;
        const float* prevb  = prev  + (size_t)b0 * H2 * W2;
        float* outb = out + (size_t)b0 * HW;

        warp_costs_kernel<<<dim3(W / 64, nb * H), 256, 0, stream>>>(
            leftb, rightb, prevb, X, H, W);

        conv_mfma< 96, 128, true><<<dim3(W / 128, nb * H), 256, 0, stream>>>(
            X, wsS + P1, b1, Y, H, W);
        conv_mfma<128, 128, true><<<dim3(W / 128, nb * H), 256, 0, stream>>>(
            Y, wsS + P2, b2, X, H, W);
        conv_mfma<128,  96, true><<<dim3(W / 128, nb * H), 256, 0, stream>>>(
            X, wsS + P3, b3, Y, H, W);
        conv_mfma< 96,  64, true><<<dim3(W / 128, nb * H), 256, 0, stream>>>(
            Y, wsS + P4, b4, X, H, W);
        conv_mfma< 64,  32, true><<<dim3(W / 128, nb * H), 256, 0, stream>>>(
            X, wsS + P5, b5, Y, H, W);

        conv_last_kernel<<<(npx + 255) / 256, 256, 0, stream>>>(
            Y, w6, b6, outb, H, W, npx);
    }
}

// Round 5
// 1008.624 us; speedup vs baseline: 8.3434x; 1.0832x over previous
//
#include <hip/hip_runtime.h>
#include <cstdint>
#include <cstddef>

// Problem dims: B=4, H=192, W=640, C=64, sr=2
// Conv chans: 69 -> 128 -> 128 -> 96 -> 64 -> 32 -> 1, 3x3 SAME, NHWC/HWIO.
//
// Round 4 -> 5: round-4 K-loop was L1-port-bound: 4 B-loads per 4 MFMAs =
// 1024 B/MFMA = 127 B/cyc demand vs ~64 B/cyc L1 -> MfmaUtil capped ~25%.
// Now waves split 2-way m x 2-way n (wave = 64px x 2 n-tiles): per kb
// 2 A-loads + 2 B-loads + 4 MFMAs -> B 512 B/MFMA (63 B/cyc, fits L1),
// A 512 B/MFMA (63 B/cyc, fits 128 B/cyc LDS). acc stays 64 AGPRs.

#define LEAKY_SLOPE 0.2f

typedef float  f32x16 __attribute__((ext_vector_type(16)));
typedef short  s16x8  __attribute__((ext_vector_type(8)));
typedef short  s16x4  __attribute__((ext_vector_type(4)));

__device__ __forceinline__ unsigned short f2bf(float f) {
    unsigned u = __float_as_uint(f);
    u += 0x7FFFu + ((u >> 16) & 1u);          // round-to-nearest-even
    return (unsigned short)(u >> 16);
}
__device__ __forceinline__ float bf2f(unsigned short s) {
    return __uint_as_float(((unsigned)s) << 16);
}
__device__ __forceinline__ float leaky(float v){ return v >= 0.f ? v : LEAKY_SLOPE * v; }

// ---------------------------------------------------------------------------
// Pack HWIO fp32 weights into bf16 B-fragment order for mfma_32x32x16_bf16:
// flat = (((dydx*KB + kb)*NT + nt)*64 + lane)*8 + j
// value = w[dydx][ci = kb*16 + (lane>>5)*8 + j][co = nt*32 + (lane&31)]
// ---------------------------------------------------------------------------
__global__ __launch_bounds__(256) void pack_weights(
    const float* __restrict__ src, short* __restrict__ dst,
    int CIN, int COUT, int KB, int NT, int total)
{
    int i = blockIdx.x * 256 + threadIdx.x;
    if (i >= total) return;
    int j    = i & 7;
    int lane = (i >> 3) & 63;
    int r    = i >> 9;
    int nt = r % NT; r /= NT;
    int kb = r % KB;
    int dydx = r / KB;
    int ci = kb * 16 + ((lane >> 5) << 3) + j;
    int co = nt * 32 + (lane & 31);
    float v = (ci < CIN) ? src[((size_t)dydx * CIN + ci) * COUT + co] : 0.f;
    dst[i] = (short)f2bf(v);
}

// ---------------------------------------------------------------------------
// Fused upsample + warp + cost-volume. Block = 64 px of one row.
// Output: bf16 [px][96]: ch0..63 = left, 64..68 = cost dots, 69..95 = 0.
// LDS strides are 72 shorts (144 B) for 16-B-aligned s16x8 access.
// ---------------------------------------------------------------------------
__global__ __launch_bounds__(256) void warp_costs_kernel(
    const float* __restrict__ left, const float* __restrict__ right,
    const float* __restrict__ prev, short* __restrict__ out,
    int H, int W)
{
    __shared__ float wt0s[68], wt1s[68];
    __shared__ int   i0s[68],  i1s[68];
    __shared__ __align__(16) short warp_s[68 * 72];  // [px -2..65][64ch]
    __shared__ __align__(16) short left_s[64 * 72];

    const int tid = threadIdx.x;
    const int w0 = blockIdx.x * 64;
    const int hh = blockIdx.y % H;
    const int bb = blockIdx.y / H;
    const int H2 = H >> 1, W2 = W >> 1;

    if (tid < 68) {
        int w = w0 - 2 + tid;
        float sy = 0.5f * (float)hh - 0.25f;
        float sx = 0.5f * (float)w  - 0.25f;
        float y0f = floorf(sy), x0f = floorf(sx);
        float fy = sy - y0f, fx = sx - x0f;
        int y0 = (int)y0f, x0 = (int)x0f;
        int y0c = min(max(y0, 0), H2 - 1), y1c = min(max(y0 + 1, 0), H2 - 1);
        int x0c = min(max(x0, 0), W2 - 1), x1c = min(max(x0 + 1, 0), W2 - 1);
        const float* pb = prev + (size_t)bb * H2 * W2;
        float p00 = pb[y0c * W2 + x0c], p01 = pb[y0c * W2 + x1c];
        float p10 = pb[y1c * W2 + x0c], p11 = pb[y1c * W2 + x1c];
        float disp = (1.f - fy) * ((1.f - fx) * p00 + fx * p01)
                   + fy * ((1.f - fx) * p10 + fx * p11);
        float cx = (float)w + disp;
        float xf0 = floorf(cx), xf1 = xf0 + 1.f;
        float xmax = (float)(W - 1);
        float x0s = fminf(fmaxf(xf0, 0.f), xmax);
        float x1s = fminf(fmaxf(xf1, 0.f), xmax);
        wt0s[tid] = (xf1 - cx) * (xf0 == x0s ? 1.f : 0.f);
        wt1s[tid] = (cx - xf0) * (xf1 == x1s ? 1.f : 0.f);
        i0s[tid] = (int)x0s;
        i1s[tid] = (int)x1s;
    }
    __syncthreads();

    const float* rrow = right + (size_t)(bb * H + hh) * W * 64;
    const float* lrow = left  + (size_t)(bb * H + hh) * W * 64;
    const size_t obase = ((size_t)(bb * H + hh) * W + w0) * 96;

    for (int u = tid; u < 68 * 16; u += 256) {
        int px = u >> 4, c4 = (u & 15) * 4;
        float a = wt0s[px], b = wt1s[px];
        const float4 r0 = *(const float4*)(rrow + (size_t)i0s[px] * 64 + c4);
        const float4 r1 = *(const float4*)(rrow + (size_t)i1s[px] * 64 + c4);
        s16x4 o;
        o[0] = (short)f2bf(a * r0.x + b * r1.x);
        o[1] = (short)f2bf(a * r0.y + b * r1.y);
        o[2] = (short)f2bf(a * r0.z + b * r1.z);
        o[3] = (short)f2bf(a * r0.w + b * r1.w);
        *(s16x4*)(warp_s + px * 72 + c4) = o;
    }
    for (int u = tid; u < 64 * 16; u += 256) {
        int px = u >> 4, c4 = (u & 15) * 4;
        const float4 l = *(const float4*)(lrow + ((size_t)(w0 + px)) * 64 + c4);
        s16x4 o;
        o[0] = (short)f2bf(l.x);
        o[1] = (short)f2bf(l.y);
        o[2] = (short)f2bf(l.z);
        o[3] = (short)f2bf(l.w);
        *(s16x4*)(left_s + px * 72 + c4) = o;
        *(s16x4*)(out + obase + (size_t)px * 96 + c4) = o;
    }
    // zero pad ch 69..95
    for (int u = tid; u < 64 * 3; u += 256) {
        int px = u / 3, c = 72 + (u % 3) * 8;
        s16x8 z = {0,0,0,0,0,0,0,0};
        *(s16x8*)(out + obase + (size_t)px * 96 + c) = z;
    }
    if (tid < 64) {
        out[obase + (size_t)tid * 96 + 69] = 0;
        out[obase + (size_t)tid * 96 + 70] = 0;
        out[obase + (size_t)tid * 96 + 71] = 0;
    }
    __syncthreads();

    // cost dots: 320 (px,d) tasks, vectorized s16x8 inner loop
    for (int u = tid; u < 64 * 5; u += 256) {
        int px = u / 5, d = u - px * 5;
        int x = w0 + px + d - 2;
        float s = 0.f;
        if (x >= 0 && x < W) {
            const short* lp = left_s + px * 72;
            const short* wq = warp_s + (px + d) * 72;
#pragma unroll
            for (int c8 = 0; c8 < 8; ++c8) {
                s16x8 l8 = *(const s16x8*)(lp + c8 * 8);
                s16x8 w8 = *(const s16x8*)(wq + c8 * 8);
#pragma unroll
                for (int k = 0; k < 8; ++k)
                    s += bf2f((unsigned short)l8[k]) * bf2f((unsigned short)w8[k]);
            }
        }
        out[obase + (size_t)px * 96 + 64 + d] = (short)f2bf(s * (1.f / 64.f));
    }
}

// ---------------------------------------------------------------------------
// bf16 MFMA 3x3 conv (implicit GEMM, mfma_f32_32x32x16_bf16).
// Block covers 128 px of one row x all COUT. TPB = 256 (4 waves) or 128 (2).
// Wave (wm, wn): wm owns 64 px (MT=2 m-tiles), wn owns NTW n-tiles.
//   NT=4: WN=2, NTW=2 | NT=3: WN=2, NTW=2 (tile 3 skipped) | NT=2: WN=2,
//   NTW=1 | NT=1: TPB=128, WN=1, NTW=1.
// Per kb: MT A ds_read_b128 + NTW B global loads + MT*NTW MFMAs
//   -> A and B both ~512 B/MFMA (fits LDS 128 B/cyc and L1 ~64 B/cyc ports).
// A staged per-dy in LDS, XOR-swizzled at 8-ch granularity.
// ---------------------------------------------------------------------------
template <int CINP, int COUT, int TPB, bool RELU>
__global__ __launch_bounds__(TPB, 3) void conv_mfma(
    const short* __restrict__ in, const short* __restrict__ wp,
    const float* __restrict__ bias, short* __restrict__ out,
    int H, int W)
{
    constexpr int KB   = CINP / 16;                  // K-steps per (dy,dx)
    constexpr int NT   = COUT / 32;                  // n-tiles total
    constexpr int CIN8 = CINP / 8;
    constexpr int SL8  = (CINP == 96) ? 16 : CIN8;   // LDS ch8-slots/px (pow2)
    constexpr int WN   = (NT >= 2) ? 2 : 1;          // n-split ways
    constexpr int WM   = (TPB / 64) / WN;            // m-split ways
    constexpr int MT   = 4 / WM;                     // m-tiles per wave
    constexpr int NTW  = (NT + WN - 1) / WN;         // n-tiles per wave
    __shared__ __align__(16) short lds[132 * SL8 * 8];

    const int tid  = threadIdx.x;
    const int lane = tid & 63;
    const int wave = tid >> 6;
    const int wn   = wave % WN;
    const int wm   = wave / WN;
    const int l31  = lane & 31;
    const int lhi  = lane >> 5;
    const int w0 = blockIdx.x * 128;
    const int hh = blockIdx.y % H;
    const int bb = blockIdx.y / H;

    f32x16 acc[MT][NTW];
#pragma unroll
    for (int mt = 0; mt < MT; ++mt)
#pragma unroll
        for (int j = 0; j < NTW; ++j)
#pragma unroll
            for (int r = 0; r < 16; ++r) acc[mt][j][r] = 0.f;

    for (int dy = 0; dy < 3; ++dy) {
        __syncthreads();
        const int h = hh + dy - 1;
        const bool rowok = (h >= 0) && (h < H);
        const short* src = in + (size_t)(bb * H + h) * W * CINP;
        for (int u = tid; u < 130 * CIN8; u += TPB) {
            int px = u / CIN8;
            int c8 = u - px * CIN8;
            int x = w0 - 1 + px;
            s16x8 v = {0,0,0,0,0,0,0,0};
            if (rowok && x >= 0 && x < W)
                v = *(const s16x8*)(src + (size_t)x * CINP + c8 * 8);
            *(s16x8*)(&lds[(px * SL8 + (c8 ^ (px & 7))) * 8]) = v;
        }
        __syncthreads();

#pragma unroll
        for (int dx = 0; dx < 3; ++dx) {
            const short* wdx = wp + (size_t)((dy * 3 + dx) * KB) * NT * 512;
#pragma unroll 2
            for (int kb = 0; kb < KB; ++kb) {
                const int c8r = kb * 2 + lhi;
                s16x8 a[MT];
#pragma unroll
                for (int mt = 0; mt < MT; ++mt) {
                    const int px = (wm * MT + mt) * 32 + l31 + dx;
                    a[mt] = *(const s16x8*)(&lds[(px * SL8 + (c8r ^ (px & 7))) * 8]);
                }
                s16x8 b[NTW];
#pragma unroll
                for (int j = 0; j < NTW; ++j) {
                    const int tile = wn * NTW + j;
                    if (tile < NT)
                        b[j] = *(const s16x8*)(wdx + ((size_t)(kb * NT + tile) * 64 + lane) * 8);
                }
#pragma unroll
                for (int j = 0; j < NTW; ++j) {
                    if (wn * NTW + j >= NT) continue;
#pragma unroll
                    for (int mt = 0; mt < MT; ++mt)
                        acc[mt][j] = __builtin_amdgcn_mfma_f32_32x32x16_bf16(
                            a[mt], b[j], acc[mt][j], 0, 0, 0);
                }
            }
        }
    }

    // epilogue: C/D layout col(co)=lane&31, row(px)=(r&3)+8*(r>>2)+4*(lane>>5)
    const size_t rowbase = (size_t)(bb * H + hh) * W + w0;
#pragma unroll
    for (int j = 0; j < NTW; ++j) {
        const int tile = wn * NTW + j;
        if (tile >= NT) continue;
        const int co = tile * 32 + l31;
        const float bv = bias[co];
#pragma unroll
        for (int mt = 0; mt < MT; ++mt) {
            const int pxb = (wm * MT + mt) * 32 + 4 * lhi;
#pragma unroll
            for (int r = 0; r < 16; ++r) {
                int px = pxb + (r & 3) + 8 * (r >> 2);
                float v = acc[mt][j][r] + bv;
                if (RELU) v = leaky(v);
                out[(rowbase + px) * COUT + co] = (short)f2bf(v);
            }
        }
    }
}

// ---------------------------------------------------------------------------
// Final conv 32 -> 1, linear, bf16 in / fp32 out. One thread per pixel.
// ---------------------------------------------------------------------------
__global__ __launch_bounds__(256) void conv_last_kernel(
    const short* __restrict__ in, const float* __restrict__ wgt,
    const float* __restrict__ bias, float* __restrict__ out,
    int H, int W, int npx)
{
    int idx = blockIdx.x * 256 + threadIdx.x;
    if (idx >= npx) return;
    int w = idx % W;
    int t = idx / W;
    int h = t % H;
    int b = t / H;

    float acc = bias[0];
#pragma unroll
    for (int dy = 0; dy < 3; ++dy) {
        int hy = h + dy - 1;
        if (hy < 0 || hy >= H) continue;
#pragma unroll
        for (int dx = 0; dx < 3; ++dx) {
            int x = w + dx - 1;
            if (x < 0 || x >= W) continue;
            const short* p = in + ((size_t)(b * H + hy) * W + x) * 32;
            const float* wk = wgt + (dy * 3 + dx) * 32;
#pragma unroll
            for (int c8 = 0; c8 < 4; ++c8) {
                s16x8 v = *(const s16x8*)(p + c8 * 8);
#pragma unroll
                for (int k = 0; k < 8; ++k)
                    acc += bf2f((unsigned short)v[k]) * wk[c8 * 8 + k];
            }
        }
    }
    out[idx] = acc;
}

// ---------------------------------------------------------------------------
extern "C" void kernel_launch(void* const* d_in, const int* in_sizes, int n_in,
                              void* d_out, int out_size, void* d_ws, size_t ws_size,
                              hipStream_t stream)
{
    constexpr int B = 4, H = 192, W = 640;
    constexpr int HW = H * W;          // 122880

    const float* left  = (const float*)d_in[0];
    const float* right = (const float*)d_in[1];
    const float* prev  = (const float*)d_in[2];
    const float* w1 = (const float*)d_in[4];
    const float* b1 = (const float*)d_in[5];
    const float* w2 = (const float*)d_in[6];
    const float* b2 = (const float*)d_in[7];
    const float* w3 = (const float*)d_in[8];
    const float* b3 = (const float*)d_in[9];
    const float* w4 = (const float*)d_in[10];
    const float* b4 = (const float*)d_in[11];
    const float* w5 = (const float*)d_in[12];
    const float* b5 = (const float*)d_in[13];
    const float* w6 = (const float*)d_in[14];
    const float* b6 = (const float*)d_in[15];
    float* out = (float*)d_out;

    // Packed-weight region (shorts), then bf16 activation ping-pong X/Y.
    constexpr int S1 = 9 * 6 * 4 * 512;   // conv1: CINP 96,  COUT 128
    constexpr int S2 = 9 * 8 * 4 * 512;   // conv2: 128 -> 128
    constexpr int S3 = 9 * 8 * 3 * 512;   // conv3: 128 -> 96
    constexpr int S4 = 9 * 6 * 2 * 512;   // conv4: 96  -> 64
    constexpr int S5 = 9 * 4 * 1 * 512;   // conv5: 64  -> 32
    constexpr int P1 = 0, P2 = P1 + S1, P3 = P2 + S2, P4 = P3 + S3, P5 = P4 + S4;
    constexpr size_t WPAD = 524288;       // 1 MiB reserved (in shorts)

    short* wsS = (short*)d_ws;
    pack_weights<<<(S1 + 255) / 256, 256, 0, stream>>>(w1, wsS + P1,  69, 128, 6, 4, S1);
    pack_weights<<<(S2 + 255) / 256, 256, 0, stream>>>(w2, wsS + P2, 128, 128, 8, 4, S2);
    pack_weights<<<(S3 + 255) / 256, 256, 0, stream>>>(w3, wsS + P3, 128,  96, 8, 3, S3);
    pack_weights<<<(S4 + 255) / 256, 256, 0, stream>>>(w4, wsS + P4,  96,  64, 6, 2, S4);
    pack_weights<<<(S5 + 255) / 256, 256, 0, stream>>>(w5, wsS + P5,  64,  32, 4, 1, S5);

    // batch tiling from ws_size (deterministic -> graph-capture safe)
    auto need = [&](int nb) -> size_t {
        return (WPAD + 2ull * nb * HW * 128) * sizeof(short);
    };
    int nb = 1;
    if (ws_size >= need(4)) nb = 4;
    else if (ws_size >= need(2)) nb = 2;

    const int H2 = H / 2, W2 = W / 2;

    for (int b0 = 0; b0 < B; b0 += nb) {
        const int npx = nb * HW;
        short* X = wsS + WPAD;
        short* Y = X + (size_t)nb * HW * 128;

        const float* leftb  = left  + (size_t)b0 * HW * 64;
        const float* rightb = right + (size_t)b0 * HW * 64;
        const float* prevb  = prev  + (size_t)b0 * H2 * W2;
        float* outb = out + (size_t)b0 * HW;

        warp_costs_kernel<<<dim3(W / 64, nb * H), 256, 0, stream>>>(
            leftb, rightb, prevb, X, H, W);

        conv_mfma< 96, 128, 256, true><<<dim3(W / 128, nb * H), 256, 0, stream>>>(
            X, wsS + P1, b1, Y, H, W);
        conv_mfma<128, 128, 256, true><<<dim3(W / 128, nb * H), 256, 0, stream>>>(
            Y, wsS + P2, b2, X, H, W);
        conv_mfma<128,  96, 256, true><<<dim3(W / 128, nb * H), 256, 0, stream>>>(
            X, wsS + P3, b3, Y, H, W);
        conv_mfma< 96,  64, 256, true><<<dim3(W / 128, nb * H), 256, 0, stream>>>(
            Y, wsS + P4, b4, X, H, W);
        conv_mfma< 64,  32, 128, true><<<dim3(W / 128, nb * H), 128, 0, stream>>>(
            X, wsS + P5, b5, Y, H, W);

        conv_last_kernel<<<(npx + 255) / 256, 256, 0, stream>>>(
            Y, w6, b6, outb, H, W, npx);
    }
}